// Round 5
// baseline (446.965 us; speedup 1.0000x reference)
//
#include <hip/hip_runtime.h>
#include <hip/hip_fp16.h>

#define EMBED 128
#define CHUNK 8             // gathers per pipeline batch
#define T_TILE 4096
#define NB_SH 10            // 1024 rows per bucket
#define BCAP 32768          // fixed per-bucket capacity (avg ~13.6K)

// ---------------- CSR build: passA (bucket sort, fixed-cap regions) ----------------

__global__ __launch_bounds__(256) void passA(const int* __restrict__ row,
                                             const int* __restrict__ col,
                                             const float* __restrict__ val,
                                             int* __restrict__ bcnt,
                                             long long* __restrict__ bedges, int E) {
    __shared__ int sh_scan[256];
    __shared__ int sh_start[256];
    __shared__ int sh_cur[256];
    __shared__ int sh_base[256];   // global (fixed-region) base per bucket
    __shared__ long long sh_data[T_TILE];
    __shared__ int sh_gpos[T_TILE];
    const int t0  = blockIdx.x * T_TILE;
    const int tid = threadIdx.x;

    sh_scan[tid] = 0;
    __syncthreads();
    #pragma unroll
    for (int i = 0; i < T_TILE / 256; ++i) {
        int idx = t0 + i * 256 + tid;
        if (idx < E) atomicAdd(&sh_scan[row[idx] >> NB_SH], 1);
    }
    __syncthreads();
    int x = sh_scan[tid];
    __syncthreads();
    for (int off = 1; off < 256; off <<= 1) {
        int t = (tid >= off) ? sh_scan[tid - off] : 0;
        __syncthreads();
        sh_scan[tid] += t;
        __syncthreads();
    }
    int excl = sh_scan[tid] - x;
    sh_start[tid] = excl;
    sh_cur[tid]   = excl;
    sh_base[tid]  = (x > 0) ? (tid * BCAP + atomicAdd(&bcnt[tid], x)) : 0;
    __syncthreads();
    #pragma unroll
    for (int i = 0; i < T_TILE / 256; ++i) {
        int idx = t0 + i * 256 + tid;
        if (idx < E) {
            int   r = row[idx];
            int   c = col[idx];
            float v = val[idx];
            int   b = r >> NB_SH;
            int   p = atomicAdd(&sh_cur[b], 1);
            unsigned lo = (unsigned)(((r & ((1 << NB_SH) - 1)) << 18) | c);
            sh_data[p] = ((long long)__float_as_int(v) << 32) | (long long)lo;
            sh_gpos[p] = sh_base[b] + (p - sh_start[b]);
        }
    }
    __syncthreads();
    int tot = sh_scan[255];
    for (int p = tid; p < tot; p += 256) {
        bedges[sh_gpos[p]] = sh_data[p];
    }
}

// ---------------- passB: per-bucket row hist + scan -> rs + exact placement ----------

__global__ __launch_bounds__(1024) void passB(const long long* __restrict__ bedges,
                                              const int* __restrict__ bcnt,
                                              int* __restrict__ rs,
                                              int2* __restrict__ edges,
                                              int N, int E, int nbuckets) {
    __shared__ int sh_hist[1024];   // row hist, then reused as cursor
    __shared__ int sh_scan[1024];
    __shared__ int sh_bc[256];
    __shared__ int sh_gbase;
    const int b    = blockIdx.x;
    const int tid  = threadIdx.x;
    const int base = b << NB_SH;
    const int cnt  = bcnt[b];
    const long long* seg = bedges + (size_t)b * BCAP;

    sh_hist[tid] = 0;
    if (tid < nbuckets) sh_bc[tid] = bcnt[tid];
    __syncthreads();
    if (tid == 0) {
        int g = 0;
        for (int j = 0; j < b; ++j) g += sh_bc[j];
        sh_gbase = g;
    }
    for (int k = tid; k < cnt; k += 1024) {
        unsigned lo = (unsigned)seg[k];
        atomicAdd(&sh_hist[lo >> 18], 1);
    }
    __syncthreads();
    int x = sh_hist[tid];
    sh_scan[tid] = x;
    __syncthreads();
    for (int off = 1; off < 1024; off <<= 1) {
        int t = (tid >= off) ? sh_scan[tid - off] : 0;
        __syncthreads();
        sh_scan[tid] += t;
        __syncthreads();
    }
    int excl = sh_scan[tid] - x;
    int gbase = sh_gbase;
    int rrow = base + tid;
    if (rrow < N) rs[rrow] = gbase + excl;
    if (b == nbuckets - 1 && tid == 0) rs[N] = E;
    sh_hist[tid] = excl;
    __syncthreads();
    for (int k = tid; k < cnt; k += 1024) {
        long long be = seg[k];
        unsigned lo = (unsigned)be;
        int p = atomicAdd(&sh_hist[lo >> 18], 1);
        edges[gbase + p] = make_int2((int)(lo & 0x3FFFF), (int)(be >> 32));
    }
}

// ---------------- fp32 -> fp16 convert (8 elems/thread, both tables) ----------------

__global__ void f32_to_f16_all(const float* __restrict__ uE, const float* __restrict__ iE,
                               __half* __restrict__ dst, int nu8, int ntot8) {
    int i = blockIdx.x * blockDim.x + threadIdx.x;
    if (i >= ntot8) return;
    const float* src = (i < nu8) ? (uE + (size_t)i * 8)
                                 : (iE + (size_t)(i - nu8) * 8);
    float4 a = ((const float4*)src)[0];
    float4 b = ((const float4*)src)[1];
    __half2 h0 = __floats2half2_rn(a.x, a.y);
    __half2 h1 = __floats2half2_rn(a.z, a.w);
    __half2 h2 = __floats2half2_rn(b.x, b.y);
    __half2 h3 = __floats2half2_rn(b.z, b.w);
    uint4 o;
    o.x = *(unsigned int*)&h0;
    o.y = *(unsigned int*)&h1;
    o.z = *(unsigned int*)&h2;
    o.w = *(unsigned int*)&h3;
    ((uint4*)dst)[i] = o;
}

// ---------------- pipelined gather loop (shared by spmm & pair) ----------------
// Rotation per stage: LOADE(t+2) -> PREP+issue gathers(t+1) -> FMA(t).
// Keeps 8 gathers + 8 edge loads in flight across every FMA phase.
// Static buffer names only (runtime-indexed arrays would spill to scratch).

#define LOADE(ED, KK)                                                        \
    do {                                                                     \
        _Pragma("unroll")                                                    \
        for (int j = 0; j < CHUNK; ++j) {                                    \
            int idx = (KK) + j;                                              \
            idx = (idx < e) ? idx : s;                                       \
            ED[j] = edges[idx];                                              \
        }                                                                    \
    } while (0)

#define PREP(VV, RAW, ED, KK, HSRC)                                          \
    do {                                                                     \
        _Pragma("unroll")                                                    \
        for (int j = 0; j < CHUNK; ++j) {                                    \
            VV[j]  = ((KK) + j < e) ? __int_as_float(ED[j].y) : 0.f;         \
            RAW[j] = *(const uint2*)(HSRC + (size_t)ED[j].x * EMBED + 4 * l32); \
        }                                                                    \
    } while (0)

#define FMA8(RAW, VV)                                                        \
    do {                                                                     \
        _Pragma("unroll")                                                    \
        for (int j = 0; j < CHUNK; ++j) {                                    \
            __half2 h01 = *(__half2*)&RAW[j].x;                              \
            __half2 h23 = *(__half2*)&RAW[j].y;                              \
            acc.x = fmaf(__half2float(h01.x), VV[j], acc.x);                 \
            acc.y = fmaf(__half2float(h01.y), VV[j], acc.y);                 \
            acc.z = fmaf(__half2float(h23.x), VV[j], acc.z);                 \
            acc.w = fmaf(__half2float(h23.y), VV[j], acc.w);                 \
        }                                                                    \
    } while (0)

#define PIPELINE_LOOP(HSRC)                                                  \
    int2  edA[CHUNK], edB[CHUNK];                                            \
    uint2 rawA[CHUNK], rawB[CHUNK];                                          \
    float vvA[CHUNK], vvB[CHUNK];                                            \
    LOADE(edA, s);                                                           \
    LOADE(edB, s + CHUNK);                                                   \
    PREP(vvA, rawA, edA, s, HSRC);                                           \
    int k = s;                                                               \
    while (true) {                                                           \
        LOADE(edA, k + 2 * CHUNK);                                           \
        PREP(vvB, rawB, edB, k + CHUNK, HSRC);                               \
        FMA8(rawA, vvA);                                                     \
        k += CHUNK; if (k >= e) break;                                       \
        LOADE(edB, k + 2 * CHUNK);                                           \
        PREP(vvA, rawA, edA, k + CHUNK, HSRC);                               \
        FMA8(rawB, vvB);                                                     \
        k += CHUNK; if (k >= e) break;                                       \
    }

// ---------------- SpMM: 2 rows/wave (32 lanes each), fp16 h, fp32 acc ----------------

__global__ void spmm_kernel(const int* __restrict__ rs, const int2* __restrict__ edges,
                            const __half* __restrict__ hin, __half* __restrict__ hout,
                            int N) {
    int gid  = blockIdx.x * blockDim.x + threadIdx.x;
    int wave = gid >> 6;
    int lane = threadIdx.x & 63;
    int half = lane >> 5;
    int l32  = lane & 31;
    int row  = wave * 2 + half;
    if (row >= N) return;
    int s = rs[row], e = rs[row + 1];
    float4 acc = make_float4(0.f, 0.f, 0.f, 0.f);

    PIPELINE_LOOP(hin)

    __half2 o0 = __floats2half2_rn(acc.x, acc.y);
    __half2 o1 = __floats2half2_rn(acc.z, acc.w);
    uint2 o;
    o.x = *(unsigned int*)&o0;
    o.y = *(unsigned int*)&o1;
    *(uint2*)(hout + (size_t)row * EMBED + 4 * l32) = o;
}

// ---------------- fused tail: per pair b, half0 = u-row, half1 = v-row ----------------

__global__ void spmm_pair(const int* __restrict__ rs, const int2* __restrict__ edges,
                          const __half* __restrict__ h1, const __half* __restrict__ h2,
                          const float* __restrict__ uE, const float* __restrict__ iE,
                          const int* __restrict__ uIdx, const int* __restrict__ vIdx,
                          float* __restrict__ out, int B, int userNum) {
    int gid  = blockIdx.x * blockDim.x + threadIdx.x;
    int wave = gid >> 6;
    int lane = threadIdx.x & 63;
    int half = lane >> 5;
    int l32  = lane & 31;
    if (wave >= B) return;
    int row;
    const float* emb;
    if (half == 0) {
        int u = uIdx[wave];
        row = u;
        emb = uE + (size_t)u * EMBED;
    } else {
        int it = vIdx[wave];
        row = userNum + it;
        emb = iE + (size_t)it * EMBED;
    }
    float4 acc = *(const float4*)(emb + 4 * l32);
    size_t ro = (size_t)row * EMBED + 4 * l32;
    uint2 r1 = *(const uint2*)(h1 + ro);
    uint2 r2 = *(const uint2*)(h2 + ro);
    {
        __half2 a0 = *(__half2*)&r1.x, a1 = *(__half2*)&r1.y;
        __half2 b0 = *(__half2*)&r2.x, b1 = *(__half2*)&r2.y;
        acc.x += __half2float(a0.x) + __half2float(b0.x);
        acc.y += __half2float(a0.y) + __half2float(b0.y);
        acc.z += __half2float(a1.x) + __half2float(b1.x);
        acc.w += __half2float(a1.y) + __half2float(b1.y);
    }
    int s = rs[row], e = rs[row + 1];

    PIPELINE_LOOP(h2)

    float ox = __shfl_xor(acc.x, 32);
    float oy = __shfl_xor(acc.y, 32);
    float oz = __shfl_xor(acc.z, 32);
    float ow = __shfl_xor(acc.w, 32);
    float sdot = acc.x * ox + acc.y * oy + acc.z * oz + acc.w * ow;
    #pragma unroll
    for (int off = 16; off > 0; off >>= 1) sdot += __shfl_down(sdot, off, 32);
    sdot += __shfl_down(sdot, 32);
    if (lane == 0) out[wave] = sdot * (1.f / 32.f);   // (acc/4)·(acc/4), x2 halves
}

// ---------------- launch ----------------

extern "C" void kernel_launch(void* const* d_in, const int* in_sizes, int n_in,
                              void* d_out, int out_size, void* d_ws, size_t ws_size,
                              hipStream_t stream) {
    const float* uE      = (const float*)d_in[0];
    const float* iE      = (const float*)d_in[1];
    const float* L_val   = (const float*)d_in[2];
    const int*   L_row   = (const int*)d_in[3];
    const int*   L_col   = (const int*)d_in[4];
    const int*   userIdx = (const int*)d_in[5];
    const int*   itemIdx = (const int*)d_in[6];

    const int userNum = in_sizes[0] / EMBED;   // 100000
    const int itemNum = in_sizes[1] / EMBED;   // 50000
    const int N = userNum + itemNum;           // 150000
    const int E = in_sizes[2];                 // 2000000
    const int B = in_sizes[5];                 // 16384
    float* out = (float*)d_out;

    char* ws = (char*)d_ws;
    size_t off = 0;
    auto alloc = [&](size_t bytes) -> void* {
        void* p = ws + off;
        off += (bytes + 1023) & ~(size_t)1023;
        return p;
    };
    const int NBUCKETS = (N + (1 << NB_SH) - 1) >> NB_SH;   // 147
    __half* h0     = (__half*)alloc((size_t)N * EMBED * 2);
    __half* h1     = (__half*)alloc((size_t)N * EMBED * 2);
    __half* h2     = (__half*)alloc((size_t)N * EMBED * 2);
    int2*   edges  = (int2*) alloc((size_t)E * 8 + 256);    // +slack for clamped prefetch
    long long* bedges = (long long*)alloc((size_t)NBUCKETS * BCAP * 8);
    int*    rs     = (int*)  alloc((size_t)(N + 1) * 4);
    int*    bcnt   = (int*)  alloc(1024);
    (void)off; (void)ws_size; (void)n_in; (void)out_size;

    const int tb = 256;

    // CSR build: 3 dispatches
    (void)hipMemsetAsync(bcnt, 0, 1024, stream);
    passA<<<(E + T_TILE - 1) / T_TILE, 256, 0, stream>>>(L_row, L_col, L_val,
                                                         bcnt, bedges, E);
    passB<<<NBUCKETS, 1024, 0, stream>>>(bedges, bcnt, rs, edges, N, E, NBUCKETS);

    // feats -> fp16 (single launch)
    const int nu8 = userNum * EMBED / 8;
    const int ntot8 = N * EMBED / 8;
    f32_to_f16_all<<<(ntot8 + tb - 1) / tb, tb, 0, stream>>>(uE, iE, h0, nu8, ntot8);

    // propagation: 8 rows per 256-thread block (2 rows/wave)
    const int spmm_blocks = (N + 7) / 8;
    spmm_kernel<<<spmm_blocks, 256, 0, stream>>>(rs, edges, h0, h1, N);
    spmm_kernel<<<spmm_blocks, 256, 0, stream>>>(rs, edges, h1, h2, N);

    // fused layer-3-restricted spmm + layer-sum + dot
    spmm_pair<<<(B + 3) / 4, 256, 0, stream>>>(rs, edges, h1, h2, uE, iE,
                                               userIdx, itemIdx, out, B, userNum);
}

// Round 6
// 349.413 us; speedup vs baseline: 1.2792x; 1.2792x over previous
//
#include <hip/hip_runtime.h>
#include <hip/hip_fp16.h>

#define EMBED 128
#define CHUNK 8             // gathers per inner batch
#define T_TILE 4096
#define NB_SH 10            // 1024 rows per bucket
#define BCAP 32768          // fixed per-bucket capacity (avg ~13.6K)

// ---------------- CSR build: passA (bucket sort, fixed-cap regions) ----------------

__global__ __launch_bounds__(256) void passA(const int* __restrict__ row,
                                             const int* __restrict__ col,
                                             const float* __restrict__ val,
                                             int* __restrict__ bcnt,
                                             long long* __restrict__ bedges, int E) {
    __shared__ int sh_scan[256];
    __shared__ int sh_start[256];
    __shared__ int sh_cur[256];
    __shared__ int sh_base[256];   // global (fixed-region) base per bucket
    __shared__ long long sh_data[T_TILE];
    __shared__ int sh_gpos[T_TILE];
    const int t0  = blockIdx.x * T_TILE;
    const int tid = threadIdx.x;

    sh_scan[tid] = 0;
    __syncthreads();
    #pragma unroll
    for (int i = 0; i < T_TILE / 256; ++i) {
        int idx = t0 + i * 256 + tid;
        if (idx < E) atomicAdd(&sh_scan[row[idx] >> NB_SH], 1);
    }
    __syncthreads();
    int x = sh_scan[tid];
    __syncthreads();
    for (int off = 1; off < 256; off <<= 1) {
        int t = (tid >= off) ? sh_scan[tid - off] : 0;
        __syncthreads();
        sh_scan[tid] += t;
        __syncthreads();
    }
    int excl = sh_scan[tid] - x;
    sh_start[tid] = excl;
    sh_cur[tid]   = excl;
    sh_base[tid]  = (x > 0) ? (tid * BCAP + atomicAdd(&bcnt[tid], x)) : 0;
    __syncthreads();
    #pragma unroll
    for (int i = 0; i < T_TILE / 256; ++i) {
        int idx = t0 + i * 256 + tid;
        if (idx < E) {
            int   r = row[idx];
            int   c = col[idx];
            float v = val[idx];
            int   b = r >> NB_SH;
            int   p = atomicAdd(&sh_cur[b], 1);
            unsigned lo = (unsigned)(((r & ((1 << NB_SH) - 1)) << 18) | c);
            sh_data[p] = ((long long)__float_as_int(v) << 32) | (long long)lo;
            sh_gpos[p] = sh_base[b] + (p - sh_start[b]);
        }
    }
    __syncthreads();
    int tot = sh_scan[255];
    for (int p = tid; p < tot; p += 256) {
        bedges[sh_gpos[p]] = sh_data[p];
    }
}

// ---------------- passB: per-bucket row hist + scan -> rs + exact placement ----------

__global__ __launch_bounds__(1024) void passB(const long long* __restrict__ bedges,
                                              const int* __restrict__ bcnt,
                                              int* __restrict__ rs,
                                              int2* __restrict__ edges,
                                              int N, int E, int nbuckets) {
    __shared__ int sh_hist[1024];   // row hist, then reused as cursor
    __shared__ int sh_scan[1024];
    __shared__ int sh_bc[256];
    __shared__ int sh_gbase;
    const int b    = blockIdx.x;
    const int tid  = threadIdx.x;
    const int base = b << NB_SH;
    const int cnt  = bcnt[b];
    const long long* seg = bedges + (size_t)b * BCAP;

    sh_hist[tid] = 0;
    if (tid < nbuckets) sh_bc[tid] = bcnt[tid];
    __syncthreads();
    if (tid == 0) {
        int g = 0;
        for (int j = 0; j < b; ++j) g += sh_bc[j];
        sh_gbase = g;
    }
    for (int k = tid; k < cnt; k += 1024) {
        unsigned lo = (unsigned)seg[k];
        atomicAdd(&sh_hist[lo >> 18], 1);
    }
    __syncthreads();
    int x = sh_hist[tid];
    sh_scan[tid] = x;
    __syncthreads();
    for (int off = 1; off < 1024; off <<= 1) {
        int t = (tid >= off) ? sh_scan[tid - off] : 0;
        __syncthreads();
        sh_scan[tid] += t;
        __syncthreads();
    }
    int excl = sh_scan[tid] - x;
    int gbase = sh_gbase;
    int rrow = base + tid;
    if (rrow < N) rs[rrow] = gbase + excl;
    if (b == nbuckets - 1 && tid == 0) rs[N] = E;
    sh_hist[tid] = excl;
    __syncthreads();
    for (int k = tid; k < cnt; k += 1024) {
        long long be = seg[k];
        unsigned lo = (unsigned)be;
        int p = atomicAdd(&sh_hist[lo >> 18], 1);
        edges[gbase + p] = make_int2((int)(lo & 0x3FFFF), (int)(be >> 32));
    }
}

// ---------------- fp32 -> fp16 convert (8 elems/thread, both tables) ----------------

__global__ void f32_to_f16_all(const float* __restrict__ uE, const float* __restrict__ iE,
                               __half* __restrict__ dst, int nu8, int ntot8) {
    int i = blockIdx.x * blockDim.x + threadIdx.x;
    if (i >= ntot8) return;
    const float* src = (i < nu8) ? (uE + (size_t)i * 8)
                                 : (iE + (size_t)(i - nu8) * 8);
    float4 a = ((const float4*)src)[0];
    float4 b = ((const float4*)src)[1];
    __half2 h0 = __floats2half2_rn(a.x, a.y);
    __half2 h1 = __floats2half2_rn(a.z, a.w);
    __half2 h2 = __floats2half2_rn(b.x, b.y);
    __half2 h3 = __floats2half2_rn(b.z, b.w);
    uint4 o;
    o.x = *(unsigned int*)&h0;
    o.y = *(unsigned int*)&h1;
    o.z = *(unsigned int*)&h2;
    o.w = *(unsigned int*)&h3;
    ((uint4*)dst)[i] = o;
}

// ---------------- gather loop: lane-held edges + shfl distribution -------------------
// Each lane loads ONE edge per 32-edge super-batch (coalesced, one load covers the
// half-wave's next 32 edges). (col,val) distributed in-register via width-32 shfl.
// Removes the per-batch edge-load latency from the critical chain; gathers stream.

#define GATHER_LOOP(HSRC)                                                     \
    for (int t = s; t < e; t += 32) {                                         \
        int ecl = t + l32;                                                    \
        ecl = (ecl < e) ? ecl : (e - 1);                                      \
        int2 myed = edges[ecl];                                               \
        int nb = e - t;                                                       \
        nb = (nb < 32) ? nb : 32;                                             \
        for (int k = 0; k < nb; k += CHUNK) {                                 \
            uint2 raw[CHUNK];                                                 \
            float vv[CHUNK];                                                  \
            _Pragma("unroll")                                                 \
            for (int j = 0; j < CHUNK; ++j) {                                 \
                int  c   = __shfl(myed.x, k + j, 32);                         \
                int  v   = __shfl(myed.y, k + j, 32);                         \
                bool ok  = (k + j) < nb;                                      \
                vv[j]    = ok ? __int_as_float(v) : 0.f;                      \
                raw[j]   = *(const uint2*)(HSRC + (size_t)c * EMBED + 4 * l32); \
            }                                                                 \
            _Pragma("unroll")                                                 \
            for (int j = 0; j < CHUNK; ++j) {                                 \
                __half2 h01 = *(__half2*)&raw[j].x;                           \
                __half2 h23 = *(__half2*)&raw[j].y;                           \
                acc.x = fmaf(__half2float(h01.x), vv[j], acc.x);              \
                acc.y = fmaf(__half2float(h01.y), vv[j], acc.y);              \
                acc.z = fmaf(__half2float(h23.x), vv[j], acc.z);              \
                acc.w = fmaf(__half2float(h23.y), vv[j], acc.w);              \
            }                                                                 \
        }                                                                     \
    }

// ---------------- SpMM: 2 rows/wave (32 lanes each), fp16 h, fp32 acc ----------------

__global__ void spmm_kernel(const int* __restrict__ rs, const int2* __restrict__ edges,
                            const __half* __restrict__ hin, __half* __restrict__ hout,
                            int N) {
    int gid  = blockIdx.x * blockDim.x + threadIdx.x;
    int wave = gid >> 6;
    int lane = threadIdx.x & 63;
    int half = lane >> 5;
    int l32  = lane & 31;
    int row  = wave * 2 + half;
    if (row >= N) return;
    int s = rs[row], e = rs[row + 1];
    float4 acc = make_float4(0.f, 0.f, 0.f, 0.f);

    GATHER_LOOP(hin)

    __half2 o0 = __floats2half2_rn(acc.x, acc.y);
    __half2 o1 = __floats2half2_rn(acc.z, acc.w);
    uint2 o;
    o.x = *(unsigned int*)&o0;
    o.y = *(unsigned int*)&o1;
    *(uint2*)(hout + (size_t)row * EMBED + 4 * l32) = o;
}

// ---------------- fused tail: per pair b, half0 = u-row, half1 = v-row ----------------

__global__ void spmm_pair(const int* __restrict__ rs, const int2* __restrict__ edges,
                          const __half* __restrict__ h1, const __half* __restrict__ h2,
                          const float* __restrict__ uE, const float* __restrict__ iE,
                          const int* __restrict__ uIdx, const int* __restrict__ vIdx,
                          float* __restrict__ out, int B, int userNum) {
    int gid  = blockIdx.x * blockDim.x + threadIdx.x;
    int wave = gid >> 6;
    int lane = threadIdx.x & 63;
    int half = lane >> 5;
    int l32  = lane & 31;
    if (wave >= B) return;
    int row;
    const float* emb;
    if (half == 0) {
        int u = uIdx[wave];
        row = u;
        emb = uE + (size_t)u * EMBED;
    } else {
        int it = vIdx[wave];
        row = userNum + it;
        emb = iE + (size_t)it * EMBED;
    }
    float4 acc = *(const float4*)(emb + 4 * l32);
    size_t ro = (size_t)row * EMBED + 4 * l32;
    uint2 r1 = *(const uint2*)(h1 + ro);
    uint2 r2 = *(const uint2*)(h2 + ro);
    {
        __half2 a0 = *(__half2*)&r1.x, a1 = *(__half2*)&r1.y;
        __half2 b0 = *(__half2*)&r2.x, b1 = *(__half2*)&r2.y;
        acc.x += __half2float(a0.x) + __half2float(b0.x);
        acc.y += __half2float(a0.y) + __half2float(b0.y);
        acc.z += __half2float(a1.x) + __half2float(b1.x);
        acc.w += __half2float(a1.y) + __half2float(b1.y);
    }
    int s = rs[row], e = rs[row + 1];

    GATHER_LOOP(h2)

    float ox = __shfl_xor(acc.x, 32);
    float oy = __shfl_xor(acc.y, 32);
    float oz = __shfl_xor(acc.z, 32);
    float ow = __shfl_xor(acc.w, 32);
    float sdot = acc.x * ox + acc.y * oy + acc.z * oz + acc.w * ow;
    #pragma unroll
    for (int off = 16; off > 0; off >>= 1) sdot += __shfl_down(sdot, off, 32);
    sdot += __shfl_down(sdot, 32);
    if (lane == 0) out[wave] = sdot * (1.f / 32.f);   // (acc/4)·(acc/4), x2 halves
}

// ---------------- launch ----------------

extern "C" void kernel_launch(void* const* d_in, const int* in_sizes, int n_in,
                              void* d_out, int out_size, void* d_ws, size_t ws_size,
                              hipStream_t stream) {
    const float* uE      = (const float*)d_in[0];
    const float* iE      = (const float*)d_in[1];
    const float* L_val   = (const float*)d_in[2];
    const int*   L_row   = (const int*)d_in[3];
    const int*   L_col   = (const int*)d_in[4];
    const int*   userIdx = (const int*)d_in[5];
    const int*   itemIdx = (const int*)d_in[6];

    const int userNum = in_sizes[0] / EMBED;   // 100000
    const int itemNum = in_sizes[1] / EMBED;   // 50000
    const int N = userNum + itemNum;           // 150000
    const int E = in_sizes[2];                 // 2000000
    const int B = in_sizes[5];                 // 16384
    float* out = (float*)d_out;

    char* ws = (char*)d_ws;
    size_t off = 0;
    auto alloc = [&](size_t bytes) -> void* {
        void* p = ws + off;
        off += (bytes + 1023) & ~(size_t)1023;
        return p;
    };
    const int NBUCKETS = (N + (1 << NB_SH) - 1) >> NB_SH;   // 147
    __half* h0     = (__half*)alloc((size_t)N * EMBED * 2);
    __half* h1     = (__half*)alloc((size_t)N * EMBED * 2);
    __half* h2     = (__half*)alloc((size_t)N * EMBED * 2);
    int2*   edges  = (int2*) alloc((size_t)E * 8 + 256);
    long long* bedges = (long long*)alloc((size_t)NBUCKETS * BCAP * 8);
    int*    rs     = (int*)  alloc((size_t)(N + 1) * 4);
    int*    bcnt   = (int*)  alloc(1024);
    (void)off; (void)ws_size; (void)n_in; (void)out_size;

    const int tb = 256;

    // CSR build: 3 dispatches
    (void)hipMemsetAsync(bcnt, 0, 1024, stream);
    passA<<<(E + T_TILE - 1) / T_TILE, 256, 0, stream>>>(L_row, L_col, L_val,
                                                         bcnt, bedges, E);
    passB<<<NBUCKETS, 1024, 0, stream>>>(bedges, bcnt, rs, edges, N, E, NBUCKETS);

    // feats -> fp16 (single launch)
    const int nu8 = userNum * EMBED / 8;
    const int ntot8 = N * EMBED / 8;
    f32_to_f16_all<<<(ntot8 + tb - 1) / tb, tb, 0, stream>>>(uE, iE, h0, nu8, ntot8);

    // propagation: 8 rows per 256-thread block (2 rows/wave)
    const int spmm_blocks = (N + 7) / 8;
    spmm_kernel<<<spmm_blocks, 256, 0, stream>>>(rs, edges, h0, h1, N);
    spmm_kernel<<<spmm_blocks, 256, 0, stream>>>(rs, edges, h1, h2, N);

    // fused layer-3-restricted spmm + layer-sum + dot
    spmm_pair<<<(B + 3) / 4, 256, 0, stream>>>(rs, edges, h1, h2, uE, iE,
                                               userIdx, itemIdx, out, B, userNum);
}

// Round 7
// 303.409 us; speedup vs baseline: 1.4731x; 1.1516x over previous
//
#include <hip/hip_runtime.h>
#include <hip/hip_fp16.h>

#define EMBED 128
#define CHUNK 8             // gathers per inner batch
#define T_TILE 4096
#define NB_SH 10            // 1024 rows per bucket
#define BCAP 32768          // fixed per-bucket capacity (avg ~13.6K)

// int8 storage: per-row symmetric quant (R4-proven, absmax 4.96e-5).
// q = rint(h*127/amax)+128 in [1,255]; h = (q-128)*s, s = amax/127.
// SpMM: acc = sum q*(v*s_col), cb = sum (v*s_col); h_out = acc - 128*cb.

// ---------------- CSR build: passA (bucket sort, fixed-cap regions) ----------------

__global__ __launch_bounds__(256) void passA(const int* __restrict__ row,
                                             const int* __restrict__ col,
                                             const float* __restrict__ val,
                                             int* __restrict__ bcnt,
                                             long long* __restrict__ bedges, int E) {
    __shared__ int sh_scan[256];
    __shared__ int sh_start[256];
    __shared__ int sh_cur[256];
    __shared__ int sh_base[256];   // global (fixed-region) base per bucket
    __shared__ long long sh_data[T_TILE];
    __shared__ int sh_gpos[T_TILE];
    const int t0  = blockIdx.x * T_TILE;
    const int tid = threadIdx.x;

    sh_scan[tid] = 0;
    __syncthreads();
    #pragma unroll
    for (int i = 0; i < T_TILE / 256; ++i) {
        int idx = t0 + i * 256 + tid;
        if (idx < E) atomicAdd(&sh_scan[row[idx] >> NB_SH], 1);
    }
    __syncthreads();
    int x = sh_scan[tid];
    __syncthreads();
    for (int off = 1; off < 256; off <<= 1) {
        int t = (tid >= off) ? sh_scan[tid - off] : 0;
        __syncthreads();
        sh_scan[tid] += t;
        __syncthreads();
    }
    int excl = sh_scan[tid] - x;
    sh_start[tid] = excl;
    sh_cur[tid]   = excl;
    sh_base[tid]  = (x > 0) ? (tid * BCAP + atomicAdd(&bcnt[tid], x)) : 0;
    __syncthreads();
    #pragma unroll
    for (int i = 0; i < T_TILE / 256; ++i) {
        int idx = t0 + i * 256 + tid;
        if (idx < E) {
            int   r = row[idx];
            int   c = col[idx];
            float v = val[idx];
            int   b = r >> NB_SH;
            int   p = atomicAdd(&sh_cur[b], 1);
            unsigned lo = (unsigned)(((r & ((1 << NB_SH) - 1)) << 18) | c);
            sh_data[p] = ((long long)__float_as_int(v) << 32) | (long long)lo;
            sh_gpos[p] = sh_base[b] + (p - sh_start[b]);
        }
    }
    __syncthreads();
    int tot = sh_scan[255];
    for (int p = tid; p < tot; p += 256) {
        bedges[sh_gpos[p]] = sh_data[p];
    }
}

// ---------------- passB: per-bucket row hist + scan -> rs + exact placement ----------

__global__ __launch_bounds__(1024) void passB(const long long* __restrict__ bedges,
                                              const int* __restrict__ bcnt,
                                              int* __restrict__ rs,
                                              int2* __restrict__ edges,
                                              int N, int E, int nbuckets) {
    __shared__ int sh_hist[1024];   // row hist, then reused as cursor
    __shared__ int sh_scan[1024];
    __shared__ int sh_bc[256];
    __shared__ int sh_gbase;
    const int b    = blockIdx.x;
    const int tid  = threadIdx.x;
    const int base = b << NB_SH;
    const int cnt  = bcnt[b];
    const long long* seg = bedges + (size_t)b * BCAP;

    sh_hist[tid] = 0;
    if (tid < nbuckets) sh_bc[tid] = bcnt[tid];
    __syncthreads();
    if (tid == 0) {
        int g = 0;
        for (int j = 0; j < b; ++j) g += sh_bc[j];
        sh_gbase = g;
    }
    for (int k = tid; k < cnt; k += 1024) {
        unsigned lo = (unsigned)seg[k];
        atomicAdd(&sh_hist[lo >> 18], 1);
    }
    __syncthreads();
    int x = sh_hist[tid];
    sh_scan[tid] = x;
    __syncthreads();
    for (int off = 1; off < 1024; off <<= 1) {
        int t = (tid >= off) ? sh_scan[tid - off] : 0;
        __syncthreads();
        sh_scan[tid] += t;
        __syncthreads();
    }
    int excl = sh_scan[tid] - x;
    int gbase = sh_gbase;
    int rrow = base + tid;
    if (rrow < N) rs[rrow] = gbase + excl;
    if (b == nbuckets - 1 && tid == 0) rs[N] = E;
    sh_hist[tid] = excl;
    __syncthreads();
    for (int k = tid; k < cnt; k += 1024) {
        long long be = seg[k];
        unsigned lo = (unsigned)be;
        int p = atomicAdd(&sh_hist[lo >> 18], 1);
        edges[gbase + p] = make_int2((int)(lo & 0x3FFFF), (int)(be >> 32));
    }
}

// ---------------- fp32 -> int8 per-row quant (2 rows/wave, 32 lanes each) -------------

__global__ void f32_to_i8_all(const float* __restrict__ uE, const float* __restrict__ iE,
                              unsigned* __restrict__ dst, float* __restrict__ sc,
                              int userNum, int N) {
    int gid  = blockIdx.x * blockDim.x + threadIdx.x;
    int wave = gid >> 6;
    int lane = threadIdx.x & 63;
    int half = lane >> 5;
    int l32  = lane & 31;
    int row  = wave * 2 + half;
    if (row >= N) return;
    const float* src = (row < userNum) ? (uE + (size_t)row * EMBED)
                                       : (iE + (size_t)(row - userNum) * EMBED);
    float4 a = *(const float4*)(src + 4 * l32);
    float am = fmaxf(fmaxf(fabsf(a.x), fabsf(a.y)), fmaxf(fabsf(a.z), fabsf(a.w)));
    #pragma unroll
    for (int off = 16; off > 0; off >>= 1)
        am = fmaxf(am, __shfl_xor(am, off));
    float s   = am * (1.f / 127.f);
    float inv = (am > 0.f) ? (127.f / am) : 0.f;
    int q0 = (int)rintf(a.x * inv) + 128;
    int q1 = (int)rintf(a.y * inv) + 128;
    int q2 = (int)rintf(a.z * inv) + 128;
    int q3 = (int)rintf(a.w * inv) + 128;
    unsigned w = (unsigned)q0 | ((unsigned)q1 << 8) | ((unsigned)q2 << 16)
               | ((unsigned)q3 << 24);
    dst[(size_t)row * 32 + l32] = w;
    if (l32 == 0) sc[row] = s;
}

// ---------------- gather loop: lane-held edges + shfl distribution, int8 h -----------
// Owner lane loads edge + its row scale once per 32-edge super-batch; (col, v*s)
// distributed in-register via width-32 shfl. Gathers are 1 dword/lane (128 B/row).

#define GATHER_LOOP_I8(HSRC, SCSRC)                                           \
    for (int t = s; t < e; t += 32) {                                         \
        int ecl = t + l32;                                                    \
        ecl = (ecl < e) ? ecl : (e - 1);                                      \
        int2 myed = edges[ecl];                                               \
        float mvs = __int_as_float(myed.y) * SCSRC[myed.x];                   \
        int nb = e - t;                                                       \
        nb = (nb < 32) ? nb : 32;                                             \
        for (int k = 0; k < nb; k += CHUNK) {                                 \
            unsigned raw[CHUNK];                                              \
            float tv[CHUNK];                                                  \
            _Pragma("unroll")                                                 \
            for (int j = 0; j < CHUNK; ++j) {                                 \
                int   c  = __shfl(myed.x, k + j, 32);                         \
                float tj = __shfl(mvs, k + j, 32);                            \
                bool ok  = (k + j) < nb;                                      \
                tv[j]    = ok ? tj : 0.f;                                     \
                raw[j]   = HSRC[(size_t)c * 32 + l32];                        \
            }                                                                 \
            _Pragma("unroll")                                                 \
            for (int j = 0; j < CHUNK; ++j) {                                 \
                unsigned r = raw[j];                                          \
                float tj = tv[j];                                             \
                cb += tj;                                                     \
                acc.x = fmaf((float)(unsigned char)(r),       tj, acc.x);     \
                acc.y = fmaf((float)(unsigned char)(r >> 8),  tj, acc.y);     \
                acc.z = fmaf((float)(unsigned char)(r >> 16), tj, acc.z);     \
                acc.w = fmaf((float)(unsigned char)(r >> 24), tj, acc.w);     \
            }                                                                 \
        }                                                                     \
    }

// ---------------- SpMM: 2 rows/wave (32 lanes each), int8 h, fp32 acc ----------------

__global__ void spmm_kernel(const int* __restrict__ rs, const int2* __restrict__ edges,
                            const unsigned* __restrict__ hin,
                            const float* __restrict__ scin,
                            unsigned* __restrict__ hout, float* __restrict__ scout,
                            int N) {
    int gid  = blockIdx.x * blockDim.x + threadIdx.x;
    int wave = gid >> 6;
    int lane = threadIdx.x & 63;
    int half = lane >> 5;
    int l32  = lane & 31;
    int row  = wave * 2 + half;
    if (row >= N) return;
    int s = rs[row], e = rs[row + 1];
    float4 acc = make_float4(0.f, 0.f, 0.f, 0.f);
    float cb = 0.f;

    GATHER_LOOP_I8(hin, scin)

    float b = 128.f * cb;
    acc.x -= b; acc.y -= b; acc.z -= b; acc.w -= b;
    // per-row quantize (max over 128 elems = 4 comps x 32 lanes)
    float am = fmaxf(fmaxf(fabsf(acc.x), fabsf(acc.y)), fmaxf(fabsf(acc.z), fabsf(acc.w)));
    #pragma unroll
    for (int off = 16; off > 0; off >>= 1)
        am = fmaxf(am, __shfl_xor(am, off));
    float sq  = am * (1.f / 127.f);
    float inv = (am > 0.f) ? (127.f / am) : 0.f;
    int q0 = (int)rintf(acc.x * inv) + 128;
    int q1 = (int)rintf(acc.y * inv) + 128;
    int q2 = (int)rintf(acc.z * inv) + 128;
    int q3 = (int)rintf(acc.w * inv) + 128;
    unsigned w = (unsigned)q0 | ((unsigned)q1 << 8) | ((unsigned)q2 << 16)
               | ((unsigned)q3 << 24);
    hout[(size_t)row * 32 + l32] = w;
    if (l32 == 0) scout[row] = sq;
}

// ---------------- fused tail: per pair b, half0 = u-row, half1 = v-row ----------------

__global__ void spmm_pair(const int* __restrict__ rs, const int2* __restrict__ edges,
                          const unsigned* __restrict__ h1, const float* __restrict__ sc1,
                          const unsigned* __restrict__ h2, const float* __restrict__ sc2,
                          const float* __restrict__ uE, const float* __restrict__ iE,
                          const int* __restrict__ uIdx, const int* __restrict__ vIdx,
                          float* __restrict__ out, int B, int userNum) {
    int gid  = blockIdx.x * blockDim.x + threadIdx.x;
    int wave = gid >> 6;
    int lane = threadIdx.x & 63;
    int half = lane >> 5;
    int l32  = lane & 31;
    if (wave >= B) return;
    int row;
    const float* emb;
    if (half == 0) {
        int u = uIdx[wave];
        row = u;
        emb = uE + (size_t)u * EMBED;
    } else {
        int it = vIdx[wave];
        row = userNum + it;
        emb = iE + (size_t)it * EMBED;
    }
    float4 acc = *(const float4*)(emb + 4 * l32);   // feats, exact fp32
    {
        unsigned r1 = h1[(size_t)row * 32 + l32];
        unsigned r2 = h2[(size_t)row * 32 + l32];
        float s1 = sc1[row];
        float s2 = sc2[row];
        acc.x += ((float)(unsigned char)(r1)       - 128.f) * s1
               + ((float)(unsigned char)(r2)       - 128.f) * s2;
        acc.y += ((float)(unsigned char)(r1 >> 8)  - 128.f) * s1
               + ((float)(unsigned char)(r2 >> 8)  - 128.f) * s2;
        acc.z += ((float)(unsigned char)(r1 >> 16) - 128.f) * s1
               + ((float)(unsigned char)(r2 >> 16) - 128.f) * s2;
        acc.w += ((float)(unsigned char)(r1 >> 24) - 128.f) * s1
               + ((float)(unsigned char)(r2 >> 24) - 128.f) * s2;
    }
    float cb = 0.f;
    int s = rs[row], e = rs[row + 1];

    GATHER_LOOP_I8(h2, sc2)

    float b = 128.f * cb;
    acc.x -= b; acc.y -= b; acc.z -= b; acc.w -= b;

    float ox = __shfl_xor(acc.x, 32);
    float oy = __shfl_xor(acc.y, 32);
    float oz = __shfl_xor(acc.z, 32);
    float ow = __shfl_xor(acc.w, 32);
    float sdot = acc.x * ox + acc.y * oy + acc.z * oz + acc.w * ow;
    #pragma unroll
    for (int off = 16; off > 0; off >>= 1) sdot += __shfl_down(sdot, off, 32);
    sdot += __shfl_down(sdot, 32);
    if (lane == 0) out[wave] = sdot * (1.f / 32.f);   // (acc/4)·(acc/4), x2 halves
}

// ---------------- launch ----------------

extern "C" void kernel_launch(void* const* d_in, const int* in_sizes, int n_in,
                              void* d_out, int out_size, void* d_ws, size_t ws_size,
                              hipStream_t stream) {
    const float* uE      = (const float*)d_in[0];
    const float* iE      = (const float*)d_in[1];
    const float* L_val   = (const float*)d_in[2];
    const int*   L_row   = (const int*)d_in[3];
    const int*   L_col   = (const int*)d_in[4];
    const int*   userIdx = (const int*)d_in[5];
    const int*   itemIdx = (const int*)d_in[6];

    const int userNum = in_sizes[0] / EMBED;   // 100000
    const int itemNum = in_sizes[1] / EMBED;   // 50000
    const int N = userNum + itemNum;           // 150000
    const int E = in_sizes[2];                 // 2000000
    const int B = in_sizes[5];                 // 16384
    float* out = (float*)d_out;

    char* ws = (char*)d_ws;
    size_t off = 0;
    auto alloc = [&](size_t bytes) -> void* {
        void* p = ws + off;
        off += (bytes + 1023) & ~(size_t)1023;
        return p;
    };
    const int NBUCKETS = (N + (1 << NB_SH) - 1) >> NB_SH;   // 147
    unsigned* h0 = (unsigned*)alloc((size_t)N * EMBED);   // int8
    unsigned* h1 = (unsigned*)alloc((size_t)N * EMBED);   // int8
    unsigned* h2 = (unsigned*)alloc((size_t)N * EMBED);   // int8
    float* sc0   = (float*)alloc((size_t)N * 4);
    float* sc1   = (float*)alloc((size_t)N * 4);
    float* sc2   = (float*)alloc((size_t)N * 4);
    int2*   edges  = (int2*) alloc((size_t)E * 8 + 256);   // +slack for clamped prefetch
    long long* bedges = (long long*)alloc((size_t)NBUCKETS * BCAP * 8);
    int*    rs     = (int*)  alloc((size_t)(N + 1) * 4);
    int*    bcnt   = (int*)  alloc(1024);
    (void)off; (void)ws_size; (void)n_in; (void)out_size;

    const int tb = 256;

    // CSR build: 3 dispatches
    (void)hipMemsetAsync(bcnt, 0, 1024, stream);
    passA<<<(E + T_TILE - 1) / T_TILE, 256, 0, stream>>>(L_row, L_col, L_val,
                                                         bcnt, bedges, E);
    passB<<<NBUCKETS, 1024, 0, stream>>>(bedges, bcnt, rs, edges, N, E, NBUCKETS);

    // feats -> int8 per-row (2 rows/wave)
    const int cv_blocks = (N + 7) / 8;
    f32_to_i8_all<<<cv_blocks, 256, 0, stream>>>(uE, iE, h0, sc0, userNum, N);

    // propagation: 8 rows per 256-thread block (2 rows/wave)
    const int spmm_blocks = (N + 7) / 8;
    spmm_kernel<<<spmm_blocks, 256, 0, stream>>>(rs, edges, h0, sc0, h1, sc1, N);
    spmm_kernel<<<spmm_blocks, 256, 0, stream>>>(rs, edges, h1, sc1, h2, sc2, N);

    // fused layer-3-restricted spmm + layer-sum + dot
    spmm_pair<<<(B + 3) / 4, 256, 0, stream>>>(rs, edges, h1, sc1, h2, sc2, uE, iE,
                                               userIdx, itemIdx, out, B, userNum);
}